// Round 1
// baseline (10903.567 us; speedup 1.0000x reference)
//
#include <hip/hip_runtime.h>

typedef float f32x4 __attribute__((ext_vector_type(4)));

constexpr int N_NODES = 100000;
constexpr int N_EDGES = 3200000;
constexpr int D = 256;          // D_IN == D_OUT
constexpr int KC = 32;          // K-chunk staged in LDS

// ---------------------------------------------------------------------------
// GEMM: H[N, 256] = X[N, 256] @ W[256, 256]      (fp32, vector ALU)
// block = 256 threads (4 waves). Tile: 64 rows x 256 cols.
// thread (tx = tid&63, ty = tid>>6) computes 16 rows x 4 cols.
// ---------------------------------------------------------------------------
__global__ __launch_bounds__(256, 2)
void gemm_xw(const float* __restrict__ X, const float* __restrict__ W,
             float* __restrict__ H, int n_rows) {
  __shared__ float Xs[64][36];          // 36-pad: rows 144B apart -> 16B aligned
  __shared__ float Ws[KC][256];

  const int tid  = threadIdx.x;
  const int row0 = blockIdx.x * 64;
  const int tx   = tid & 63;
  const int ty   = tid >> 6;
  const int col  = tx * 4;

  float acc[16][4];
#pragma unroll
  for (int i = 0; i < 16; ++i)
#pragma unroll
    for (int j = 0; j < 4; ++j) acc[i][j] = 0.f;

  // staging coords
  const int xr = tid >> 3;              // 0..31 (plus +32 for second load)
  const int xk = (tid & 7) * 4;         // k offset 0..28
  const int wk = tid >> 6;              // 0..3
  const int wc = (tid & 63) * 4;        // 0..252

  for (int kc = 0; kc < D; kc += KC) {
    // ---- stage X tile: rows row0..row0+63, k = kc..kc+31
    {
      int r1 = row0 + xr;        if (r1 >= n_rows) r1 = n_rows - 1;
      int r2 = row0 + xr + 32;   if (r2 >= n_rows) r2 = n_rows - 1;
      f32x4 a = *reinterpret_cast<const f32x4*>(X + (size_t)r1 * D + kc + xk);
      f32x4 b = *reinterpret_cast<const f32x4*>(X + (size_t)r2 * D + kc + xk);
      *reinterpret_cast<f32x4*>(&Xs[xr][xk])      = a;
      *reinterpret_cast<f32x4*>(&Xs[xr + 32][xk]) = b;
    }
    // ---- stage W tile: k = kc..kc+31, all 256 cols
#pragma unroll
    for (int jj = 0; jj < 8; ++jj) {
      int kk = wk + jj * 4;
      f32x4 w = *reinterpret_cast<const f32x4*>(W + (size_t)(kc + kk) * D + wc);
      *reinterpret_cast<f32x4*>(&Ws[kk][wc]) = w;
    }
    __syncthreads();

    // ---- compute
#pragma unroll
    for (int k4 = 0; k4 < KC; k4 += 4) {
      f32x4 wv0 = *reinterpret_cast<const f32x4*>(&Ws[k4 + 0][col]);
      f32x4 wv1 = *reinterpret_cast<const f32x4*>(&Ws[k4 + 1][col]);
      f32x4 wv2 = *reinterpret_cast<const f32x4*>(&Ws[k4 + 2][col]);
      f32x4 wv3 = *reinterpret_cast<const f32x4*>(&Ws[k4 + 3][col]);
#pragma unroll
      for (int i = 0; i < 16; ++i) {
        f32x4 xv = *reinterpret_cast<const f32x4*>(&Xs[ty * 16 + i][k4]);
#pragma unroll
        for (int j = 0; j < 4; ++j) {
          acc[i][j] += xv[0] * wv0[j];
          acc[i][j] += xv[1] * wv1[j];
          acc[i][j] += xv[2] * wv2[j];
          acc[i][j] += xv[3] * wv3[j];
        }
      }
    }
    __syncthreads();
  }

  // ---- write H
#pragma unroll
  for (int i = 0; i < 16; ++i) {
    int row = row0 + ty * 16 + i;
    if (row < n_rows) {
      f32x4 o = {acc[i][0], acc[i][1], acc[i][2], acc[i][3]};
      *reinterpret_cast<f32x4*>(H + (size_t)row * D + col) = o;
    }
  }
}

// ---------------------------------------------------------------------------
// out[i, :] = bias[:]   (init before scatter-add)
// ---------------------------------------------------------------------------
__global__ __launch_bounds__(256)
void init_bias(float* __restrict__ out, const float* __restrict__ bias) {
  const int i = blockIdx.x * 256 + threadIdx.x;     // over N*D/4 float4s
  const f32x4 b = reinterpret_cast<const f32x4*>(bias)[i & 63];
  reinterpret_cast<f32x4*>(out)[i] = b;
}

// ---------------------------------------------------------------------------
// scatter: out[row[e], :] += val[e] * H[col[e], :]
// one wave per edge-quad; lane l handles dims 4l..4l+3
// ---------------------------------------------------------------------------
constexpr int EPW = 4;  // edges per wave
__global__ __launch_bounds__(256)
void scatter_add(const int* __restrict__ arow, const int* __restrict__ acol,
                 const float* __restrict__ aval, const float* __restrict__ H,
                 float* __restrict__ out) {
  const int wave = (blockIdx.x << 2) | (threadIdx.x >> 6);
  const int lane = threadIdx.x & 63;
  const int e0 = wave * EPW;
#pragma unroll
  for (int i = 0; i < EPW; ++i) {
    const int e = e0 + i;
    const int r = arow[e];
    const int c = acol[e];
    const float v = aval[e];
    f32x4 h4 = *reinterpret_cast<const f32x4*>(H + (size_t)c * D + lane * 4);
    float* o = out + (size_t)r * D + lane * 4;
    atomicAdd(o + 0, h4[0] * v);
    atomicAdd(o + 1, h4[1] * v);
    atomicAdd(o + 2, h4[2] * v);
    atomicAdd(o + 3, h4[3] * v);
  }
}

// ---------------------------------------------------------------------------
extern "C" void kernel_launch(void* const* d_in, const int* in_sizes, int n_in,
                              void* d_out, int out_size, void* d_ws, size_t ws_size,
                              hipStream_t stream) {
  const float* X    = (const float*)d_in[0];
  const int*   arow = (const int*)  d_in[1];
  const int*   acol = (const int*)  d_in[2];
  const float* aval = (const float*)d_in[3];
  const float* W    = (const float*)d_in[4];
  const float* bias = (const float*)d_in[5];
  float* out = (float*)d_out;
  float* H   = (float*)d_ws;                 // 100000*256*4 = 102.4 MB

  // 1) H = X @ W
  gemm_xw<<<(N_NODES + 63) / 64, 256, 0, stream>>>(X, W, H, N_NODES);

  // 2) out = bias (broadcast)
  init_bias<<<(N_NODES * D / 4) / 256, 256, 0, stream>>>(out, bias);

  // 3) out[row] += val * H[col]
  scatter_add<<<N_EDGES / (4 * EPW), 256, 0, stream>>>(arow, acol, aval, H, out);
}

// Round 2
// 1049.044 us; speedup vs baseline: 10.3938x; 10.3938x over previous
//
#include <hip/hip_runtime.h>

typedef float f32x4 __attribute__((ext_vector_type(4)));

constexpr int N_NODES = 100000;
constexpr int N_EDGES = 3200000;
constexpr int D = 256;          // D_IN == D_OUT
constexpr int KC = 32;          // GEMM K-chunk staged in LDS

// ---- workspace layout (bytes) ----
constexpr size_t OFF_H        = 0;                       // 102,400,000
constexpr size_t OFF_COUNTS   = 102400000;               // 400,000
constexpr size_t OFF_ROWSTART = 102800000;               // 400,004 (N+1 ints)
constexpr size_t OFF_BSUM     = 103200256;               // 98 ints
constexpr size_t OFF_BOFF     = 103200768;               // 98 ints
constexpr size_t OFF_PACKED   = 103201280;               // 3.2M int2 = 25.6 MB
constexpr size_t WS_NEEDED    = OFF_PACKED + (size_t)N_EDGES * 8;

constexpr int SCAN_BLK = 98;    // ceil(100000 / 1024)

// ---------------------------------------------------------------------------
// GEMM: H[N, 256] = X[N, 256] @ W[256, 256]      (fp32, vector ALU)
// ---------------------------------------------------------------------------
__global__ __launch_bounds__(256, 2)
void gemm_xw(const float* __restrict__ X, const float* __restrict__ W,
             float* __restrict__ H, int n_rows) {
  __shared__ float Xs[64][36];
  __shared__ float Ws[KC][256];

  const int tid  = threadIdx.x;
  const int row0 = blockIdx.x * 64;
  const int tx   = tid & 63;
  const int ty   = tid >> 6;
  const int col  = tx * 4;

  float acc[16][4];
#pragma unroll
  for (int i = 0; i < 16; ++i)
#pragma unroll
    for (int j = 0; j < 4; ++j) acc[i][j] = 0.f;

  const int xr = tid >> 3;
  const int xk = (tid & 7) * 4;
  const int wk = tid >> 6;
  const int wc = (tid & 63) * 4;

  for (int kc = 0; kc < D; kc += KC) {
    {
      int r1 = row0 + xr;        if (r1 >= n_rows) r1 = n_rows - 1;
      int r2 = row0 + xr + 32;   if (r2 >= n_rows) r2 = n_rows - 1;
      f32x4 a = *reinterpret_cast<const f32x4*>(X + (size_t)r1 * D + kc + xk);
      f32x4 b = *reinterpret_cast<const f32x4*>(X + (size_t)r2 * D + kc + xk);
      *reinterpret_cast<f32x4*>(&Xs[xr][xk])      = a;
      *reinterpret_cast<f32x4*>(&Xs[xr + 32][xk]) = b;
    }
#pragma unroll
    for (int jj = 0; jj < 8; ++jj) {
      int kk = wk + jj * 4;
      f32x4 w = *reinterpret_cast<const f32x4*>(W + (size_t)(kc + kk) * D + wc);
      *reinterpret_cast<f32x4*>(&Ws[kk][wc]) = w;
    }
    __syncthreads();

#pragma unroll
    for (int k4 = 0; k4 < KC; k4 += 4) {
      f32x4 wv0 = *reinterpret_cast<const f32x4*>(&Ws[k4 + 0][col]);
      f32x4 wv1 = *reinterpret_cast<const f32x4*>(&Ws[k4 + 1][col]);
      f32x4 wv2 = *reinterpret_cast<const f32x4*>(&Ws[k4 + 2][col]);
      f32x4 wv3 = *reinterpret_cast<const f32x4*>(&Ws[k4 + 3][col]);
#pragma unroll
      for (int i = 0; i < 16; ++i) {
        f32x4 xv = *reinterpret_cast<const f32x4*>(&Xs[ty * 16 + i][k4]);
#pragma unroll
        for (int j = 0; j < 4; ++j) {
          acc[i][j] += xv[0] * wv0[j];
          acc[i][j] += xv[1] * wv1[j];
          acc[i][j] += xv[2] * wv2[j];
          acc[i][j] += xv[3] * wv3[j];
        }
      }
    }
    __syncthreads();
  }

#pragma unroll
  for (int i = 0; i < 16; ++i) {
    int row = row0 + ty * 16 + i;
    if (row < n_rows) {
      f32x4 o = {acc[i][0], acc[i][1], acc[i][2], acc[i][3]};
      *reinterpret_cast<f32x4*>(H + (size_t)row * D + col) = o;
    }
  }
}

// ---------------------------------------------------------------------------
// Counting-sort pipeline
// ---------------------------------------------------------------------------
__global__ __launch_bounds__(256)
void hist_rows(const int* __restrict__ arow, int* __restrict__ counts) {
  for (int i = blockIdx.x * 256 + threadIdx.x; i < N_EDGES; i += gridDim.x * 256)
    atomicAdd(&counts[arow[i]], 1);
}

// phase A: per-block (1024-item) sums
__global__ __launch_bounds__(256)
void scan_block_sums(const int* __restrict__ counts, int* __restrict__ bsum) {
  __shared__ int sd[256];
  const int b = blockIdx.x, t = threadIdx.x;
  const int base = b * 1024 + t * 4;
  int s = 0;
#pragma unroll
  for (int j = 0; j < 4; ++j) { int idx = base + j; if (idx < N_NODES) s += counts[idx]; }
  sd[t] = s; __syncthreads();
  for (int off = 128; off > 0; off >>= 1) {
    if (t < off) sd[t] += sd[t + off];
    __syncthreads();
  }
  if (t == 0) bsum[b] = sd[0];
}

// phase B: exclusive scan of the 98 block sums (single block)
__global__ __launch_bounds__(128)
void scan_bsums(const int* __restrict__ bsum, int* __restrict__ boff,
                int* __restrict__ row_start) {
  __shared__ int sd[128];
  const int t = threadIdx.x;
  int v = (t < SCAN_BLK) ? bsum[t] : 0;
  sd[t] = v; __syncthreads();
  for (int off = 1; off < 128; off <<= 1) {
    int x = (t >= off) ? sd[t - off] : 0;
    __syncthreads();
    sd[t] += x;
    __syncthreads();
  }
  if (t < SCAN_BLK) boff[t] = sd[t] - v;   // exclusive
  if (t == 0) row_start[N_NODES] = N_EDGES;
}

// phase C: block-local exclusive scan + block offset -> row_start
__global__ __launch_bounds__(256)
void scan_write(const int* __restrict__ counts, const int* __restrict__ boff,
                int* __restrict__ row_start) {
  __shared__ int sd[256];
  const int b = blockIdx.x, t = threadIdx.x;
  const int base = b * 1024 + t * 4;
  int v[4];
#pragma unroll
  for (int j = 0; j < 4; ++j) v[j] = (base + j < N_NODES) ? counts[base + j] : 0;
  int l0 = 0, l1 = v[0], l2 = v[0] + v[1], l3 = v[0] + v[1] + v[2];
  int s = l3 + v[3];
  sd[t] = s; __syncthreads();
  for (int off = 1; off < 256; off <<= 1) {
    int x = (t >= off) ? sd[t - off] : 0;
    __syncthreads();
    sd[t] += x;
    __syncthreads();
  }
  const int o = boff[b] + sd[t] - s;
  if (base + 0 < N_NODES) row_start[base + 0] = o + l0;
  if (base + 1 < N_NODES) row_start[base + 1] = o + l1;
  if (base + 2 < N_NODES) row_start[base + 2] = o + l2;
  if (base + 3 < N_NODES) row_start[base + 3] = o + l3;
}

// bin edges into CSR order. counts[r] holds degree; atomicSub hands out slots.
__global__ __launch_bounds__(256)
void bin_edges(const int* __restrict__ arow, const int* __restrict__ acol,
               const float* __restrict__ aval, int* __restrict__ counts,
               const int* __restrict__ row_start, int2* __restrict__ packed) {
  for (int i = blockIdx.x * 256 + threadIdx.x; i < N_EDGES; i += gridDim.x * 256) {
    const int r = arow[i];
    const int old = atomicSub(&counts[r], 1);
    const int slot = row_start[r] + old - 1;
    packed[slot] = make_int2(acol[i], __float_as_int(aval[i]));
  }
}

// ---------------------------------------------------------------------------
// Segmented reduce: one wave per row. lane l owns dims 4l..4l+3.
// ---------------------------------------------------------------------------
__global__ __launch_bounds__(256)
void row_reduce(const int* __restrict__ row_start, const int2* __restrict__ packed,
                const float* __restrict__ H, const float* __restrict__ bias,
                float* __restrict__ out) {
  const int wave = blockIdx.x * 4 + (threadIdx.x >> 6);
  const int lane = threadIdx.x & 63;
  if (wave >= N_NODES) return;
  const int s = row_start[wave];
  const int e = row_start[wave + 1];

  f32x4 acc0 = {0.f, 0.f, 0.f, 0.f};
  f32x4 acc1 = {0.f, 0.f, 0.f, 0.f};
  int i = s;
  for (; i + 2 <= e; i += 2) {
    const int2 p0 = packed[i];
    const int2 p1 = packed[i + 1];
    const f32x4 h0 = *reinterpret_cast<const f32x4*>(H + (size_t)p0.x * D + lane * 4);
    const f32x4 h1 = *reinterpret_cast<const f32x4*>(H + (size_t)p1.x * D + lane * 4);
    const float v0 = __int_as_float(p0.y);
    const float v1 = __int_as_float(p1.y);
#pragma unroll
    for (int j = 0; j < 4; ++j) { acc0[j] += v0 * h0[j]; acc1[j] += v1 * h1[j]; }
  }
  if (i < e) {
    const int2 p = packed[i];
    const f32x4 h = *reinterpret_cast<const f32x4*>(H + (size_t)p.x * D + lane * 4);
    const float v = __int_as_float(p.y);
#pragma unroll
    for (int j = 0; j < 4; ++j) acc0[j] += v * h[j];
  }
  const f32x4 b = *reinterpret_cast<const f32x4*>(bias + lane * 4);
  f32x4 o;
#pragma unroll
  for (int j = 0; j < 4; ++j) o[j] = acc0[j] + acc1[j] + b[j];
  *reinterpret_cast<f32x4*>(out + (size_t)wave * D + lane * 4) = o;
}

// ---------------------------------------------------------------------------
// Fallback path (round-0 atomic version) if ws_size is too small
// ---------------------------------------------------------------------------
__global__ __launch_bounds__(256)
void init_bias(float* __restrict__ out, const float* __restrict__ bias) {
  const int i = blockIdx.x * 256 + threadIdx.x;
  const f32x4 b = reinterpret_cast<const f32x4*>(bias)[i & 63];
  reinterpret_cast<f32x4*>(out)[i] = b;
}

__global__ __launch_bounds__(256)
void scatter_add(const int* __restrict__ arow, const int* __restrict__ acol,
                 const float* __restrict__ aval, const float* __restrict__ H,
                 float* __restrict__ out) {
  const int wave = (blockIdx.x << 2) | (threadIdx.x >> 6);
  const int lane = threadIdx.x & 63;
  const int e0 = wave * 4;
#pragma unroll
  for (int i = 0; i < 4; ++i) {
    const int e = e0 + i;
    const int r = arow[e];
    const int c = acol[e];
    const float v = aval[e];
    f32x4 h4 = *reinterpret_cast<const f32x4*>(H + (size_t)c * D + lane * 4);
    float* o = out + (size_t)r * D + lane * 4;
    atomicAdd(o + 0, h4[0] * v);
    atomicAdd(o + 1, h4[1] * v);
    atomicAdd(o + 2, h4[2] * v);
    atomicAdd(o + 3, h4[3] * v);
  }
}

// ---------------------------------------------------------------------------
extern "C" void kernel_launch(void* const* d_in, const int* in_sizes, int n_in,
                              void* d_out, int out_size, void* d_ws, size_t ws_size,
                              hipStream_t stream) {
  const float* X    = (const float*)d_in[0];
  const int*   arow = (const int*)  d_in[1];
  const int*   acol = (const int*)  d_in[2];
  const float* aval = (const float*)d_in[3];
  const float* W    = (const float*)d_in[4];
  const float* bias = (const float*)d_in[5];
  float* out = (float*)d_out;

  char* ws = (char*)d_ws;
  float* H         = (float*)(ws + OFF_H);
  int*   counts    = (int*)  (ws + OFF_COUNTS);
  int*   row_start = (int*)  (ws + OFF_ROWSTART);
  int*   bsum      = (int*)  (ws + OFF_BSUM);
  int*   boff      = (int*)  (ws + OFF_BOFF);
  int2*  packed    = (int2*) (ws + OFF_PACKED);

  // 1) H = X @ W
  gemm_xw<<<(N_NODES + 63) / 64, 256, 0, stream>>>(X, W, H, N_NODES);

  if (ws_size >= WS_NEEDED) {
    // 2) CSR build: histogram -> scan -> bin
    hipMemsetAsync(counts, 0, N_NODES * sizeof(int), stream);
    hist_rows<<<2048, 256, 0, stream>>>(arow, counts);
    scan_block_sums<<<SCAN_BLK, 256, 0, stream>>>(counts, bsum);
    scan_bsums<<<1, 128, 0, stream>>>(bsum, boff, row_start);
    scan_write<<<SCAN_BLK, 256, 0, stream>>>(counts, boff, row_start);
    bin_edges<<<2048, 256, 0, stream>>>(arow, acol, aval, counts, row_start, packed);

    // 3) segmented reduce, bias folded in
    row_reduce<<<(N_NODES + 3) / 4, 256, 0, stream>>>(row_start, packed, H, bias, out);
  } else {
    // fallback: atomic scatter (round-0 path)
    init_bias<<<(N_NODES * D / 4) / 256, 256, 0, stream>>>(out, bias);
    scatter_add<<<N_EDGES / 16, 256, 0, stream>>>(arow, acol, aval, H, out);
  }
}

// Round 4
// 718.455 us; speedup vs baseline: 15.1764x; 1.4601x over previous
//
#include <hip/hip_runtime.h>
#include <hip/hip_bf16.h>

typedef float  f32x4  __attribute__((ext_vector_type(4)));
typedef short  s16x8  __attribute__((ext_vector_type(8)));
typedef unsigned short u16x4 __attribute__((ext_vector_type(4)));
typedef unsigned short u16x8 __attribute__((ext_vector_type(8)));

constexpr int N_NODES = 100000;
constexpr int N_EDGES = 3200000;
constexpr int D = 256;

// ---- workspace layout (bytes) ----
constexpr size_t OFF_H        = 0;                       // bf16 H: 51,200,000
constexpr size_t OFF_COUNTS   = 51200000;                // 400,000
constexpr size_t OFF_ROWSTART = 51600000;                // 400,004 -> pad
constexpr size_t OFF_BSUM     = 52000256;
constexpr size_t OFF_BOFF     = 52000768;
constexpr size_t OFF_WT       = 52001280;                // bf16 W^T: 131,072
constexpr size_t OFF_PACKED   = 52132352;                // 3.2M int2 = 25.6 MB
constexpr int SCAN_BLK = 98;                             // ceil(100000/1024)

__device__ inline unsigned short f2bf(float f) {
  __hip_bfloat16 h = __float2bfloat16(f);                // RNE
  return *reinterpret_cast<unsigned short*>(&h);
}

// ---------------------------------------------------------------------------
// W[256][256] fp32  ->  Wt[j][k] bf16 (transpose + cast), 64 blocks x 32x32
// ---------------------------------------------------------------------------
__global__ __launch_bounds__(256)
void wt_cast(const float* __restrict__ W, unsigned short* __restrict__ Wt) {
  __shared__ float Ws[32][33];
  const int bx = blockIdx.x & 7, by = blockIdx.x >> 3;
  const int k0 = by * 32, j0 = bx * 32;
  const int t = threadIdx.x;
  const int tr = t >> 3, tc = (t & 7) * 4;
  f32x4 v = *reinterpret_cast<const f32x4*>(W + (size_t)(k0 + tr) * D + j0 + tc);
#pragma unroll
  for (int i = 0; i < 4; ++i) Ws[tr][tc + i] = v[i];
  __syncthreads();
  u16x4 o = { f2bf(Ws[tc + 0][tr]), f2bf(Ws[tc + 1][tr]),
              f2bf(Ws[tc + 2][tr]), f2bf(Ws[tc + 3][tr]) };
  *reinterpret_cast<u16x4*>(Wt + (size_t)(j0 + tr) * D + k0 + tc) = o;
}

// ---------------------------------------------------------------------------
// GEMM (bf16 MFMA): Hb[N,256] = bf16(X[N,256] fp32) @ Wt^T
// BM=128, BN=256 (full), BK=32. 256 thr = 4 waves; wave w: rows w*32..w*32+31.
// Per wave: 2 m-frags x 16 n-frags of 16x16, mfma_f32_16x16x32_bf16.
// LDS XOR-swizzle: byte ^= ((row&3)<<4)  (write granule 8B/16B, read 16B).
// ---------------------------------------------------------------------------
__global__ __launch_bounds__(256, 2)
void gemm_mfma(const float* __restrict__ X, const unsigned short* __restrict__ Wt,
               unsigned short* __restrict__ Hb) {
  __shared__ char As[128 * 64];   // 128 rows x 32 bf16 (64B)
  __shared__ char Bs[256 * 64];   // 256 cols x 32 bf16 (64B)

  const int t    = threadIdx.x;
  const int l    = t & 63;
  const int w    = t >> 6;
  const int row0 = blockIdx.x * 128;
  const int m_base = w * 32;

  f32x4 acc[2][16];
#pragma unroll
  for (int mi = 0; mi < 2; ++mi)
#pragma unroll
    for (int ni = 0; ni < 16; ++ni) acc[mi][ni] = (f32x4){0.f, 0.f, 0.f, 0.f};

  for (int kc = 0; kc < D; kc += 32) {
    // stage A: 128x32 fp32 -> bf16
#pragma unroll
    for (int i = 0; i < 4; ++i) {
      const int lin = i * 256 + t;
      const int r = lin >> 3, g = lin & 7;
      int row = row0 + r; if (row >= N_NODES) row = N_NODES - 1;
      f32x4 v = *reinterpret_cast<const f32x4*>(X + (size_t)row * D + kc + g * 4);
      u16x4 o = { f2bf(v[0]), f2bf(v[1]), f2bf(v[2]), f2bf(v[3]) };
      *reinterpret_cast<u16x4*>(As + r * 64 + ((g * 8) ^ ((r & 3) << 4))) = o;
    }
    // stage B: 256 cols x 32 k from Wt (already bf16, contiguous)
#pragma unroll
    for (int i = 0; i < 4; ++i) {
      const int lin = i * 256 + t;
      const int j = lin >> 2, g = lin & 3;
      u16x8 v = *reinterpret_cast<const u16x8*>(Wt + (size_t)j * D + kc + g * 8);
      *reinterpret_cast<u16x8*>(Bs + j * 64 + ((g * 16) ^ ((j & 3) << 4))) = v;
    }
    __syncthreads();

    s16x8 a[2];
#pragma unroll
    for (int mi = 0; mi < 2; ++mi) {
      const int r = m_base + mi * 16 + (l & 15);
      a[mi] = *reinterpret_cast<const s16x8*>(
          As + r * 64 + (((l >> 4) * 16) ^ ((r & 3) << 4)));
    }
#pragma unroll
    for (int ni = 0; ni < 16; ++ni) {
      const int j = ni * 16 + (l & 15);
      s16x8 b = *reinterpret_cast<const s16x8*>(
          Bs + j * 64 + (((l >> 4) * 16) ^ ((j & 3) << 4)));
      acc[0][ni] = __builtin_amdgcn_mfma_f32_16x16x32_bf16(a[0], b, acc[0][ni], 0, 0, 0);
      acc[1][ni] = __builtin_amdgcn_mfma_f32_16x16x32_bf16(a[1], b, acc[1][ni], 0, 0, 0);
    }
    __syncthreads();
  }

  // epilogue: D-frag col = ni*16 + (l&15), row = m_base + mi*16 + (l>>4)*4 + reg
#pragma unroll
  for (int mi = 0; mi < 2; ++mi)
#pragma unroll
    for (int ni = 0; ni < 16; ++ni)
#pragma unroll
      for (int r = 0; r < 4; ++r) {
        const int row = row0 + m_base + mi * 16 + ((l >> 4) << 2) + r;
        if (row < N_NODES)
          Hb[(size_t)row * D + ni * 16 + (l & 15)] = f2bf(acc[mi][ni][r]);
      }
}

// ---------------------------------------------------------------------------
// Counting-sort CSR build
// ---------------------------------------------------------------------------
__global__ __launch_bounds__(256)
void hist_rows(const int* __restrict__ arow, int* __restrict__ counts) {
  for (int i = blockIdx.x * 256 + threadIdx.x; i < N_EDGES; i += gridDim.x * 256)
    atomicAdd(&counts[arow[i]], 1);
}

__global__ __launch_bounds__(256)
void scan_block_sums(const int* __restrict__ counts, int* __restrict__ bsum) {
  __shared__ int sd[256];
  const int b = blockIdx.x, t = threadIdx.x;
  const int base = b * 1024 + t * 4;
  int s = 0;
#pragma unroll
  for (int j = 0; j < 4; ++j) { int idx = base + j; if (idx < N_NODES) s += counts[idx]; }
  sd[t] = s; __syncthreads();
  for (int off = 128; off > 0; off >>= 1) {
    if (t < off) sd[t] += sd[t + off];
    __syncthreads();
  }
  if (t == 0) bsum[b] = sd[0];
}

__global__ __launch_bounds__(128)
void scan_bsums(const int* __restrict__ bsum, int* __restrict__ boff,
                int* __restrict__ row_start) {
  __shared__ int sd[128];
  const int t = threadIdx.x;
  int v = (t < SCAN_BLK) ? bsum[t] : 0;
  sd[t] = v; __syncthreads();
  for (int off = 1; off < 128; off <<= 1) {
    int x = (t >= off) ? sd[t - off] : 0;
    __syncthreads();
    sd[t] += x;
    __syncthreads();
  }
  if (t < SCAN_BLK) boff[t] = sd[t] - v;
  if (t == 0) row_start[N_NODES] = N_EDGES;
}

__global__ __launch_bounds__(256)
void scan_write(const int* __restrict__ counts, const int* __restrict__ boff,
                int* __restrict__ row_start) {
  __shared__ int sd[256];
  const int b = blockIdx.x, t = threadIdx.x;
  const int base = b * 1024 + t * 4;
  int v[4];
#pragma unroll
  for (int j = 0; j < 4; ++j) v[j] = (base + j < N_NODES) ? counts[base + j] : 0;
  int l0 = 0, l1 = v[0], l2 = v[0] + v[1], l3 = v[0] + v[1] + v[2];
  int s = l3 + v[3];
  sd[t] = s; __syncthreads();
  for (int off = 1; off < 256; off <<= 1) {
    int x = (t >= off) ? sd[t - off] : 0;
    __syncthreads();
    sd[t] += x;
    __syncthreads();
  }
  const int o = boff[b] + sd[t] - s;
  if (base + 0 < N_NODES) row_start[base + 0] = o + l0;
  if (base + 1 < N_NODES) row_start[base + 1] = o + l1;
  if (base + 2 < N_NODES) row_start[base + 2] = o + l2;
  if (base + 3 < N_NODES) row_start[base + 3] = o + l3;
}

__global__ __launch_bounds__(256)
void bin_edges(const int* __restrict__ arow, const int* __restrict__ acol,
               const float* __restrict__ aval, int* __restrict__ counts,
               const int* __restrict__ row_start, int2* __restrict__ packed) {
  for (int i = blockIdx.x * 256 + threadIdx.x; i < N_EDGES; i += gridDim.x * 256) {
    const int r = arow[i];
    const int old = atomicSub(&counts[r], 1);
    packed[row_start[r] + old - 1] = make_int2(acol[i], __float_as_int(aval[i]));
  }
}

// ---------------------------------------------------------------------------
// Segmented reduce over bf16 H: wave per row, lane l owns dims 4l..4l+3.
// ---------------------------------------------------------------------------
__device__ inline f32x4 bf4_to_f4(u16x4 h) {
  f32x4 r;
#pragma unroll
  for (int j = 0; j < 4; ++j) r[j] = __uint_as_float(((unsigned)h[j]) << 16);
  return r;
}

__global__ __launch_bounds__(256)
void row_reduce(const int* __restrict__ row_start, const int2* __restrict__ packed,
                const unsigned short* __restrict__ Hb, const float* __restrict__ bias,
                float* __restrict__ out) {
  const int row = blockIdx.x * 4 + (threadIdx.x >> 6);
  const int l = threadIdx.x & 63;
  if (row >= N_NODES) return;
  const int s = row_start[row];
  const int e = row_start[row + 1];

  f32x4 a0 = {0.f,0.f,0.f,0.f}, a1 = a0, a2 = a0, a3 = a0;
  int i = s;
  for (; i + 4 <= e; i += 4) {
    const int2 p0 = packed[i],     p1 = packed[i + 1];
    const int2 p2 = packed[i + 2], p3 = packed[i + 3];
    const f32x4 h0 = bf4_to_f4(*reinterpret_cast<const u16x4*>(Hb + (size_t)p0.x * D + l * 4));
    const f32x4 h1 = bf4_to_f4(*reinterpret_cast<const u16x4*>(Hb + (size_t)p1.x * D + l * 4));
    const f32x4 h2 = bf4_to_f4(*reinterpret_cast<const u16x4*>(Hb + (size_t)p2.x * D + l * 4));
    const f32x4 h3 = bf4_to_f4(*reinterpret_cast<const u16x4*>(Hb + (size_t)p3.x * D + l * 4));
    const float v0 = __int_as_float(p0.y), v1 = __int_as_float(p1.y);
    const float v2 = __int_as_float(p2.y), v3 = __int_as_float(p3.y);
#pragma unroll
    for (int j = 0; j < 4; ++j) {
      a0[j] += v0 * h0[j]; a1[j] += v1 * h1[j];
      a2[j] += v2 * h2[j]; a3[j] += v3 * h3[j];
    }
  }
  for (; i < e; ++i) {
    const int2 p = packed[i];
    const f32x4 h = bf4_to_f4(*reinterpret_cast<const u16x4*>(Hb + (size_t)p.x * D + l * 4));
    const float v = __int_as_float(p.y);
#pragma unroll
    for (int j = 0; j < 4; ++j) a0[j] += v * h[j];
  }
  const f32x4 b = *reinterpret_cast<const f32x4*>(bias + l * 4);
  f32x4 o;
#pragma unroll
  for (int j = 0; j < 4; ++j) o[j] = (a0[j] + a1[j]) + (a2[j] + a3[j]) + b[j];
  *reinterpret_cast<f32x4*>(out + (size_t)row * D + l * 4) = o;
}

// ---------------------------------------------------------------------------
extern "C" void kernel_launch(void* const* d_in, const int* in_sizes, int n_in,
                              void* d_out, int out_size, void* d_ws, size_t ws_size,
                              hipStream_t stream) {
  const float* X    = (const float*)d_in[0];
  const int*   arow = (const int*)  d_in[1];
  const int*   acol = (const int*)  d_in[2];
  const float* aval = (const float*)d_in[3];
  const float* W    = (const float*)d_in[4];
  const float* bias = (const float*)d_in[5];
  float* out = (float*)d_out;

  char* ws = (char*)d_ws;
  unsigned short* Hb        = (unsigned short*)(ws + OFF_H);
  int*            counts    = (int*)  (ws + OFF_COUNTS);
  int*            row_start = (int*)  (ws + OFF_ROWSTART);
  int*            bsum      = (int*)  (ws + OFF_BSUM);
  int*            boff      = (int*)  (ws + OFF_BOFF);
  unsigned short* Wt        = (unsigned short*)(ws + OFF_WT);
  int2*           packed    = (int2*) (ws + OFF_PACKED);

  // 1) W -> Wt (bf16, transposed); then Hb = bf16(X @ W) via MFMA
  wt_cast<<<64, 256, 0, stream>>>(W, Wt);
  gemm_mfma<<<(N_NODES + 127) / 128, 256, 0, stream>>>(X, Wt, Hb);

  // 2) CSR build
  hipMemsetAsync(counts, 0, N_NODES * sizeof(int), stream);
  hist_rows<<<2048, 256, 0, stream>>>(arow, counts);
  scan_block_sums<<<SCAN_BLK, 256, 0, stream>>>(counts, bsum);
  scan_bsums<<<1, 128, 0, stream>>>(bsum, boff, row_start);
  scan_write<<<SCAN_BLK, 256, 0, stream>>>(counts, boff, row_start);
  bin_edges<<<2048, 256, 0, stream>>>(arow, acol, aval, counts, row_start, packed);

  // 3) segmented reduce (bias folded)
  row_reduce<<<(N_NODES + 3) / 4, 256, 0, stream>>>(row_start, packed, Hb, bias, out);
}